// Round 8
// baseline (748.933 us; speedup 1.0000x reference)
//
#include <hip/hip_runtime.h>
#include <math.h>

#define HID 128
#define ET  64          // edges per block (edge MLP), 1 M-tile per wave
#define K1  288         // padded K for layer 1 (268 -> 9*32)
#define Z1S 136         // S LDS stride in bf16
#define Z2S 69          // z2 LDS stride in fp32
#define SMS 136         // fused-kernel mean/h LDS stride in bf16 (272 B -> 2-way banks, free)

typedef __attribute__((ext_vector_type(8))) short short8;   // 8 bf16 = 4 VGPRs
typedef __attribute__((ext_vector_type(4))) float floatx4;  // MFMA accumulator

static __device__ __forceinline__ unsigned short f2bf(float v) {
    unsigned u = __float_as_uint(v);
    u += 0x7fffu + ((u >> 16) & 1u);   // round-to-nearest-even
    return (unsigned short)(u >> 16);
}
static __device__ __forceinline__ float bf2f_lo(unsigned u) { return __uint_as_float(u << 16); }
static __device__ __forceinline__ float bf2f_hi(unsigned u) { return __uint_as_float(u & 0xffff0000u); }
static __device__ __forceinline__ float bfs2f(short s) {
    return __uint_as_float(((unsigned)(unsigned short)s) << 16);
}

// ---------- CSR build ----------
__global__ void hist_kernel(const int* __restrict__ dst, unsigned* __restrict__ deg, int E) {
    int e = blockIdx.x * 256 + threadIdx.x;
    if (e < E) atomicAdd(&deg[dst[e]], 1u);
}

__global__ __launch_bounds__(256) void scan_partial(const unsigned* __restrict__ deg,
        unsigned* __restrict__ off, unsigned* __restrict__ bsum, int N) {
    int t = threadIdx.x;
    int base = blockIdx.x * 2048 + t * 8;
    unsigned v[8]; unsigned run = 0;
#pragma unroll
    for (int i = 0; i < 8; i++) {
        int g = base + i;
        unsigned d = (g < N) ? deg[g] : 0u;
        v[i] = run; run += d;
    }
    __shared__ unsigned s[256];
    s[t] = run; __syncthreads();
    for (int o2 = 1; o2 < 256; o2 <<= 1) {
        unsigned x = (t >= o2) ? s[t - o2] : 0u;
        __syncthreads();
        s[t] += x;
        __syncthreads();
    }
    unsigned texcl = (t > 0) ? s[t - 1] : 0u;
    if (t == 255) bsum[blockIdx.x] = s[255];
#pragma unroll
    for (int i = 0; i < 8; i++) {
        int g = base + i;
        if (g < N) off[g] = texcl + v[i];
    }
}

__global__ void scan_bsum(unsigned* bsum, int B) {   // B <= 64, single wave inclusive
    int t = threadIdx.x;
    unsigned v = (t < B) ? bsum[t] : 0u;
    for (int o = 1; o < 64; o <<= 1) {
        unsigned x = __shfl_up(v, o);
        if (t >= o) v += x;
    }
    if (t < B) bsum[t] = v;
}

__global__ void scan_add(unsigned* __restrict__ off, const unsigned* __restrict__ bsum, int N) {
    int g = blockIdx.x * 256 + threadIdx.x;
    if (g >= N) return;
    int blk = g >> 11;
    if (blk > 0) off[g] += bsum[blk - 1];
}

// fills: csrS[pos]=src, csrD[pos]=dst, csrE[pos]=edge id, rank[e]=pos
__global__ void csr_fill(const int* __restrict__ src, const int* __restrict__ dst,
                         const unsigned* __restrict__ off, unsigned* __restrict__ cur,
                         int* __restrict__ csrS, int* __restrict__ csrD,
                         int* __restrict__ csrE, int* __restrict__ rank, int E) {
    int e = blockIdx.x * 256 + threadIdx.x;
    if (e >= E) return;
    int d = dst[e];
    unsigned p = off[d] + atomicAdd(&cur[d], 1u);
    csrS[p] = src[e];
    csrD[p] = d;
    csrE[p] = e;
    rank[e] = (int)p;
}

// ---------- node projection (writes bf16 h) ----------
__global__ void node_proj_kernel(const float* __restrict__ x, const float* __restrict__ W,
                                 const float* __restrict__ b, unsigned short* __restrict__ hbf, int N) {
    int i = blockIdx.x * 256 + threadIdx.x;   // over N*64, 2 cols/thread
    if (i >= N * 64) return;
    int n = i >> 6, f2 = (i & 63) * 2;
    float a0 = b[f2], a1 = b[f2 + 1];
#pragma unroll
    for (int k = 0; k < 5; k++) {
        float xv = x[n * 5 + k];
        a0 = fmaf(xv, W[k * HID + f2], a0);
        a1 = fmaf(xv, W[k * HID + f2 + 1], a1);
    }
    unsigned pack = ((unsigned)f2bf(a1) << 16) | f2bf(a0);
    *(unsigned*)&hbf[(size_t)n * HID + f2] = pack;
}

// ---------- merged weight prep ----------
__global__ void prep_weights(const float* __restrict__ W1, const float* __restrict__ W2,
                             const float* __restrict__ Wl, const float* __restrict__ Wr,
                             unsigned short* __restrict__ W1T, unsigned short* __restrict__ W2T,
                             unsigned short* __restrict__ WST) {
    int i = blockIdx.x * 256 + threadIdx.x;
    if (i < 128 * K1) {
        int n = i / K1, k = i - n * K1;
        W1T[i] = (k < 268) ? f2bf(W1[k * HID + n]) : (unsigned short)0;
        return;
    }
    int j = i - 128 * K1;
    if (j < 64 * HID) {
        int n = j >> 7, k = j & 127;
        W2T[j] = f2bf(W2[k * 64 + n]);
        return;
    }
    int m = j - 64 * HID;
    if (m < 3 * 128 * 256) {
        int l = m >> 15, rem = m & 32767, n = rem >> 8, k = rem & 255;
        float v = (k < 128) ? Wl[l * 16384 + k * 128 + n] : Wr[l * 16384 + (k - 128) * 128 + n];
        WST[m] = f2bf(v);
    }
}

// ---------- fused agg + SAGE (+ optional P/Q epilogue) ----------
// Phase 1: aggregate means for the block's 128 nodes into LDS (no meanbf buffer).
// Phase 2: [128 x 256] @ [256 x 128] MFMA + bias + LN + ReLU.
//   doPQ==0: write h to hOut (ping-pong buffer; never in-place -> no cross-block race).
//   doPQ==1: transpose h through LDS, compute P=h@W1a, Q=h@W1b, write only P,Q.
__global__ __launch_bounds__(256) void agg_sage_fused(
    const unsigned short* __restrict__ hIn, unsigned short* __restrict__ hOut,
    unsigned short* __restrict__ Pout, unsigned short* __restrict__ Qout,
    const int* __restrict__ csr, const unsigned* __restrict__ off,
    const unsigned* __restrict__ degu,
    const unsigned short* __restrict__ WT, const float* __restrict__ bl,
    const float* __restrict__ g, const float* __restrict__ bet,
    const unsigned short* __restrict__ W1T, int doPQ, int N)
{
    __shared__ __align__(16) unsigned short smean[128 * SMS];   // 34816 B
    const int t = threadIdx.x, wave = t >> 6, lane = t & 63;
    const int blkBase = blockIdx.x * 128;

    // ---- phase 1: mean aggregation into LDS ----
    {
        const int grp = lane >> 4, c = lane & 15;
        for (int p = 0; p < 8; p++) {
            int idx = p * 16 + wave * 4 + grp;
            int n = blkBase + idx;
            int nc = n < N ? n : N - 1;
            unsigned o = off[nc];
            unsigned d = (n < N) ? degu[nc] : 0u;
            unsigned dmax = d;
            dmax = max(dmax, (unsigned)__shfl_xor((int)dmax, 16));
            dmax = max(dmax, (unsigned)__shfl_xor((int)dmax, 32));
            float acc[8] = {0.f, 0.f, 0.f, 0.f, 0.f, 0.f, 0.f, 0.f};
            for (unsigned i = 0; i < dmax; i += 8) {
                uint4 v[8];
#pragma unroll
                for (int j = 0; j < 8; j++) {
                    unsigned pp = (i + j < d) ? o + i + j : 0u;
                    int s = csr[pp];
                    v[j] = *(const uint4*)&hIn[(size_t)s * HID + c * 8];
                }
#pragma unroll
                for (int j = 0; j < 8; j++) {
                    if (i + j < d) {
                        acc[0] += bf2f_lo(v[j].x); acc[1] += bf2f_hi(v[j].x);
                        acc[2] += bf2f_lo(v[j].y); acc[3] += bf2f_hi(v[j].y);
                        acc[4] += bf2f_lo(v[j].z); acc[5] += bf2f_hi(v[j].z);
                        acc[6] += bf2f_lo(v[j].w); acc[7] += bf2f_hi(v[j].w);
                    }
                }
            }
            float inv = d ? 1.f / (float)d : 0.f;
            uint4 pk;
            pk.x = ((unsigned)f2bf(acc[1] * inv) << 16) | f2bf(acc[0] * inv);
            pk.y = ((unsigned)f2bf(acc[3] * inv) << 16) | f2bf(acc[2] * inv);
            pk.z = ((unsigned)f2bf(acc[5] * inv) << 16) | f2bf(acc[4] * inv);
            pk.w = ((unsigned)f2bf(acc[7] * inv) << 16) | f2bf(acc[6] * inv);
            *(uint4*)&smean[idx * SMS + c * 8] = pk;
        }
    }
    __syncthreads();

    // ---- phase 2: SAGE GEMM ----
    const int ln15 = lane & 15, quad = lane >> 4;

    short8 af[2][8];
#pragma unroll
    for (int tt = 0; tt < 2; tt++) {
        int idx = tt * 64 + wave * 16 + ln15;
        int m = blkBase + idx;
        int mc = m < N ? m : N - 1;
#pragma unroll
        for (int kt = 0; kt < 4; kt++)
            af[tt][kt] = *(const short8*)&smean[idx * SMS + kt * 32 + quad * 8];
#pragma unroll
        for (int kt = 0; kt < 4; kt++)
            af[tt][4 + kt] = *(const short8*)&hIn[(size_t)mc * HID + kt * 32 + quad * 8];
    }

    floatx4 acc[2][8];
#pragma unroll
    for (int nt = 0; nt < 8; nt++) {
        floatx4 a0 = {0.f, 0.f, 0.f, 0.f}, a1 = {0.f, 0.f, 0.f, 0.f};
#pragma unroll
        for (int kt = 0; kt < 8; kt++) {
            short8 b = *(const short8*)&WT[(nt * 16 + ln15) * 256 + kt * 32 + quad * 8];
            a0 = __builtin_amdgcn_mfma_f32_16x16x32_bf16(af[0][kt], b, a0, 0, 0, 0);
            a1 = __builtin_amdgcn_mfma_f32_16x16x32_bf16(af[1][kt], b, a1, 0, 0, 0);
        }
        acc[0][nt] = a0; acc[1][nt] = a1;
    }

    float blv[8], gv[8], bv[8];
#pragma unroll
    for (int nt = 0; nt < 8; nt++) {
        int col = nt * 16 + ln15;
        blv[nt] = bl[col]; gv[nt] = g[col]; bv[nt] = bet[col];
    }

    if (doPQ) __syncthreads();   // all mean A-frag reads done before smean is overwritten

#pragma unroll
    for (int tt = 0; tt < 2; tt++) {
#pragma unroll
        for (int r = 0; r < 4; r++) {
            float s = 0.f;
#pragma unroll
            for (int nt = 0; nt < 8; nt++) s += acc[tt][nt][r] + blv[nt];
            s += __shfl_xor(s, 1); s += __shfl_xor(s, 2);
            s += __shfl_xor(s, 4); s += __shfl_xor(s, 8);
            float mu = s * (1.f / 128.f);
            float q = 0.f;
#pragma unroll
            for (int nt = 0; nt < 8; nt++) { float c = acc[tt][nt][r] + blv[nt] - mu; q += c * c; }
            q += __shfl_xor(q, 1); q += __shfl_xor(q, 2);
            q += __shfl_xor(q, 4); q += __shfl_xor(q, 8);
            float rstd = rsqrtf(q * (1.f / 128.f) + 1e-5f);
            int idx2 = tt * 64 + wave * 16 + quad * 4 + r;
            int node = blkBase + idx2;
#pragma unroll
            for (int nt = 0; nt < 8; nt++) {
                float y = fmaxf((acc[tt][nt][r] + blv[nt] - mu) * rstd * gv[nt] + bv[nt], 0.f);
                float yp = __shfl_xor(y, 1);
                unsigned pack = ((unsigned)f2bf(yp) << 16) | f2bf(y);
                if (!doPQ) {
                    if (node < N && !(ln15 & 1))
                        *(unsigned*)&hOut[(size_t)node * HID + nt * 16 + ln15] = pack;
                } else {
                    if (!(ln15 & 1))    // write all 128 rows (invalid rows are discarded later)
                        *(unsigned*)&smean[idx2 * SMS + nt * 16 + ln15] = pack;
                }
            }
        }
    }

    if (doPQ) {
        __syncthreads();   // h transpose complete
        short8 hf[2][4];
#pragma unroll
        for (int tt = 0; tt < 2; tt++)
#pragma unroll
            for (int kt = 0; kt < 4; kt++)
                hf[tt][kt] = *(const short8*)&smean[(tt * 64 + wave * 16 + ln15) * SMS + kt * 32 + quad * 8];

#pragma unroll
        for (int sel = 0; sel < 2; sel++) {
            unsigned short* outp = sel ? Qout : Pout;
            int koff = sel ? 128 : 0;
#pragma unroll
            for (int nt = 0; nt < 8; nt++) {
                floatx4 a0 = {0.f, 0.f, 0.f, 0.f}, a1 = {0.f, 0.f, 0.f, 0.f};
#pragma unroll
                for (int kt = 0; kt < 4; kt++) {
                    short8 b = *(const short8*)&W1T[(size_t)(nt * 16 + ln15) * K1 + koff + kt * 32 + quad * 8];
                    a0 = __builtin_amdgcn_mfma_f32_16x16x32_bf16(hf[0][kt], b, a0, 0, 0, 0);
                    a1 = __builtin_amdgcn_mfma_f32_16x16x32_bf16(hf[1][kt], b, a1, 0, 0, 0);
                }
                floatx4 aa[2] = {a0, a1};
#pragma unroll
                for (int tt = 0; tt < 2; tt++) {
#pragma unroll
                    for (int r = 0; r < 4; r++) {
                        float y = aa[tt][r];
                        float yp = __shfl_xor(y, 1);
                        int node = blkBase + tt * 64 + wave * 16 + quad * 4 + r;
                        if (node < N && !(ln15 & 1)) {
                            unsigned pack = ((unsigned)f2bf(yp) << 16) | f2bf(y);
                            *(unsigned*)&outp[(size_t)node * HID + nt * 16 + ln15] = pack;
                        }
                    }
                }
            }
        }
    }
}

// ---------- edge MLP: z1 = relu(P[src]+Q[dst]+eattr@W1c+b1); 64 pos/block ----------
__global__ __launch_bounds__(256) void edge_mlp_mfma(
    const unsigned short* __restrict__ Pbf, const unsigned short* __restrict__ Qbf,
    const int* __restrict__ csrS, const int* __restrict__ csrD, const int* __restrict__ csrE,
    const float* __restrict__ eattr,
    const unsigned short* __restrict__ W1T, const float* __restrict__ b1,
    const unsigned short* __restrict__ W2T, const float* __restrict__ b2,
    const float* __restrict__ W3, const float* __restrict__ b3,
    float* __restrict__ tmp, int E)
{
    const int t = threadIdx.x;
    const int eBase = blockIdx.x * ET;
    __shared__ __align__(16) char smem[ET * Z2S * 4];   // 17664 B: S bf16 [64][136] / z2 fp32 [64][69]
    unsigned short* sS = (unsigned short*)smem;
    float* sZ2 = (float*)smem;

    const int wave = t >> 6, lane = t & 63;
    const int ln15 = lane & 15, quad = lane >> 4;
    const int rowb = wave * 16 + ln15;
    const int pos = eBase + rowb;
    const int pc = pos < E ? pos : E - 1;
    const int rs = csrS[pc], rd = csrD[pc], re = csrE[pc];

    short8 pf[4], qf[4];
#pragma unroll
    for (int kt = 0; kt < 4; kt++)
        pf[kt] = *(const short8*)&Pbf[(size_t)rs * HID + kt * 32 + quad * 8];
#pragma unroll
    for (int kt = 0; kt < 4; kt++)
        qf[kt] = *(const short8*)&Qbf[(size_t)rd * HID + kt * 32 + quad * 8];

    short8 ef = {0, 0, 0, 0, 0, 0, 0, 0};
    if (pos < E) {
        const float* ep = eattr + (size_t)re * 12;
        if (quad == 0) {
            float4 p0 = *(const float4*)ep, p1 = *(const float4*)(ep + 4);
            ef[0] = (short)f2bf(p0.x); ef[1] = (short)f2bf(p0.y);
            ef[2] = (short)f2bf(p0.z); ef[3] = (short)f2bf(p0.w);
            ef[4] = (short)f2bf(p1.x); ef[5] = (short)f2bf(p1.y);
            ef[6] = (short)f2bf(p1.z); ef[7] = (short)f2bf(p1.w);
        } else if (quad == 1) {
            float4 p2 = *(const float4*)(ep + 8);
            ef[0] = (short)f2bf(p2.x); ef[1] = (short)f2bf(p2.y);
            ef[2] = (short)f2bf(p2.z); ef[3] = (short)f2bf(p2.w);
        }
    }

    // S = eattr @ W1c + b1 (the K=[256,288) slice of W1T), written to LDS in C-layout (bf16)
#pragma unroll
    for (int nt = 0; nt < 8; nt++) {
        floatx4 sa = {0.f, 0.f, 0.f, 0.f};
        short8 b = *(const short8*)&W1T[(size_t)(nt * 16 + ln15) * K1 + 256 + quad * 8];
        sa = __builtin_amdgcn_mfma_f32_16x16x32_bf16(ef, b, sa, 0, 0, 0);
        float bias = b1[nt * 16 + ln15];
#pragma unroll
        for (int r = 0; r < 4; r++) {
            float y = sa[r] + bias;     // no relu yet
            float yp = __shfl_xor(y, 1);
            if (!(ln15 & 1)) {
                int row = wave * 16 + quad * 4 + r;
                unsigned pk = ((unsigned)f2bf(yp) << 16) | f2bf(y);
                *(unsigned*)&sS[row * Z1S + nt * 16 + ln15] = pk;
            }
        }
    }
    __syncthreads();

    // z1 = relu(P + Q + S) in registers (A-layout)
    short8 zf[4];
#pragma unroll
    for (int kt = 0; kt < 4; kt++) {
        short8 s8 = *(const short8*)&sS[rowb * Z1S + kt * 32 + quad * 8];
        short8 z;
#pragma unroll
        for (int j = 0; j < 8; j++) {
            float v = bfs2f(pf[kt][j]) + bfs2f(qf[kt][j]) + bfs2f(s8[j]);
            z[j] = (short)f2bf(fmaxf(v, 0.f));
        }
        zf[kt] = z;
    }
    __syncthreads();    // all S reads done before z2 overlays

    // layer 2: [64 x 128] -> [64 x 64]
#pragma unroll
    for (int nt = 0; nt < 4; nt++) {
        floatx4 a = {0.f, 0.f, 0.f, 0.f};
#pragma unroll
        for (int kt = 0; kt < 4; kt++) {
            short8 b = *(const short8*)&W2T[(nt * 16 + ln15) * HID + kt * 32 + quad * 8];
            a = __builtin_amdgcn_mfma_f32_16x16x32_bf16(zf[kt], b, a, 0, 0, 0);
        }
        float bias = b2[nt * 16 + ln15];
#pragma unroll
        for (int r = 0; r < 4; r++) {
            int row = wave * 16 + quad * 4 + r;
            sZ2[row * Z2S + nt * 16 + ln15] = fmaxf(a[r] + bias, 0.f);
        }
    }
    __syncthreads();

    // layer 3 + softplus: 4 threads per edge (16 FMAs + 2 shuffles each)
    {
        int eo = t >> 2, q = t & 3;
        int p = eBase + eo;
        float a3 = 0.f;
        const float* z2 = sZ2 + eo * Z2S + q * 16;
#pragma unroll
        for (int k = 0; k < 16; k++) a3 = fmaf(z2[k], W3[q * 16 + k], a3);
        a3 += __shfl_xor(a3, 1);
        a3 += __shfl_xor(a3, 2);
        if (q == 0 && p < E) {
            a3 += b3[0];
            tmp[p] = fmaxf(a3, 0.f) + log1pf(expf(-fabsf(a3)));
        }
    }
}

// ---------- restore original edge order: out[e] = tmp[rank[e]] ----------
__global__ void remap_out(const float* __restrict__ tmp, const int* __restrict__ rank,
                          float* __restrict__ out, int E) {
    int e = blockIdx.x * 256 + threadIdx.x;
    if (e < E) out[e] = tmp[rank[e]];
}

extern "C" void kernel_launch(void* const* d_in, const int* in_sizes, int n_in,
                              void* d_out, int out_size, void* d_ws, size_t ws_size,
                              hipStream_t stream) {
    const float* x       = (const float*)d_in[0];
    const int*   ei      = (const int*)d_in[1];
    const float* eattr   = (const float*)d_in[2];
    const float* node_W  = (const float*)d_in[3];
    const float* node_b  = (const float*)d_in[4];
    const float* sage_Wl = (const float*)d_in[5];
    const float* sage_bl = (const float*)d_in[6];
    const float* sage_Wr = (const float*)d_in[7];
    const float* ln_g    = (const float*)d_in[8];
    const float* ln_b    = (const float*)d_in[9];
    const float* W1 = (const float*)d_in[10];
    const float* b1 = (const float*)d_in[11];
    const float* W2 = (const float*)d_in[12];
    const float* b2 = (const float*)d_in[13];
    const float* W3 = (const float*)d_in[14];
    const float* b3 = (const float*)d_in[15];
    float* out = (float*)d_out;

    const int N = in_sizes[0] / 5;
    const int E = in_sizes[1] / 2;
    const int* src  = ei;
    const int* dstp = ei + E;

    char* ws = (char*)d_ws;
    size_t cur_off = 0;
    auto alloc = [&](size_t bytes) { size_t p = cur_off; cur_off = (cur_off + bytes + 255) & ~(size_t)255; return p; };
    unsigned short* hA     = (unsigned short*)(ws + alloc((size_t)N * HID * 2));
    unsigned short* hB     = (unsigned short*)(ws + alloc((size_t)N * HID * 2));  // also P
    unsigned short* Qb     = (unsigned short*)(ws + alloc((size_t)N * HID * 2));
    int*            csrS   = (int*)(ws + alloc((size_t)E * 4));
    int*            csrD   = (int*)(ws + alloc((size_t)E * 4));
    int*            csrE   = (int*)(ws + alloc((size_t)E * 4));
    int*            rank   = (int*)(ws + alloc((size_t)E * 4));
    float*          tmpo   = (float*)(ws + alloc((size_t)E * 4));
    unsigned*       degu   = (unsigned*)(ws + alloc((size_t)N * 4));
    unsigned*       curp   = (unsigned*)(ws + alloc((size_t)N * 4));
    unsigned*       offs   = (unsigned*)(ws + alloc((size_t)N * 4));
    unsigned*       bsum   = (unsigned*)(ws + alloc(64 * 4));
    unsigned short* W1T    = (unsigned short*)(ws + alloc(128 * K1 * 2));
    unsigned short* W2T    = (unsigned short*)(ws + alloc(64 * HID * 2));
    unsigned short* WST    = (unsigned short*)(ws + alloc(3 * 128 * 256 * 2));

    hipMemsetAsync(degu, 0, (size_t)N * sizeof(unsigned), stream);
    hipMemsetAsync(curp, 0, (size_t)N * sizeof(unsigned), stream);
    hist_kernel<<<(E + 255) / 256, 256, 0, stream>>>(dstp, degu, E);
    int NB = (N + 2047) / 2048;   // 49 for N=100000, fits the 64-lane bsum scan
    scan_partial<<<NB, 256, 0, stream>>>(degu, offs, bsum, N);
    scan_bsum<<<1, 64, 0, stream>>>(bsum, NB);
    scan_add<<<(N + 255) / 256, 256, 0, stream>>>(offs, bsum, N);
    csr_fill<<<(E + 255) / 256, 256, 0, stream>>>(src, dstp, offs, curp, csrS, csrD, csrE, rank, E);

    int prepTotal = 128 * K1 + 64 * HID + 3 * 128 * 256;
    prep_weights<<<(prepTotal + 255) / 256, 256, 0, stream>>>(W1, W2, sage_Wl, sage_Wr, W1T, W2T, WST);

    node_proj_kernel<<<(N * 64 + 255) / 256, 256, 0, stream>>>(x, node_W, node_b, hA, N);

    int nblk = (N + 127) / 128;
    // layer 0: hA -> hB;  layer 1: hB -> hA;  layer 2: hA -> P(hB), Q(Qb)
    agg_sage_fused<<<nblk, 256, 0, stream>>>(hA, hB, nullptr, nullptr, csrS, offs, degu,
        WST + 0 * 128 * 256, sage_bl + 0 * HID, ln_g + 0 * HID, ln_b + 0 * HID, W1T, 0, N);
    agg_sage_fused<<<nblk, 256, 0, stream>>>(hB, hA, nullptr, nullptr, csrS, offs, degu,
        WST + 1 * 128 * 256, sage_bl + 1 * HID, ln_g + 1 * HID, ln_b + 1 * HID, W1T, 0, N);
    agg_sage_fused<<<nblk, 256, 0, stream>>>(hA, nullptr, hB, Qb, csrS, offs, degu,
        WST + 2 * 128 * 256, sage_bl + 2 * HID, ln_g + 2 * HID, ln_b + 2 * HID, W1T, 1, N);

    edge_mlp_mfma<<<(E + ET - 1) / ET, 256, 0, stream>>>(
        hB, Qb, csrS, csrD, csrE, eattr, W1T, b1, W2T, b2, W3, b3, tmpo, E);
    remap_out<<<(E + 255) / 256, 256, 0, stream>>>(tmpo, rank, out, E);
}

// Round 9
// 670.008 us; speedup vs baseline: 1.1178x; 1.1178x over previous
//
#include <hip/hip_runtime.h>
#include <hip/hip_bf16.h>
#include <math.h>

#define HID 128
#define ET  64          // edges per block (edge MLP), 1 M-tile per wave
#define K1  288         // padded K for layer 1 (268 -> 9*32)
#define Z1S 136         // S LDS stride in bf16
#define Z2S 69          // z2 LDS stride in fp32

typedef __attribute__((ext_vector_type(8))) short short8;   // 8 bf16 = 4 VGPRs
typedef __attribute__((ext_vector_type(4))) float floatx4;  // MFMA accumulator

// HW packed convert: v_cvt_pk_bf16_f32 (RNE), lo -> low 16 bits
static __device__ __forceinline__ unsigned pack2bf(float lo, float hi) {
    __hip_bfloat162 v = __float22bfloat162_rn(float2{lo, hi});
    union { __hip_bfloat162 b; unsigned u; } cv; cv.b = v; return cv.u;
}
static __device__ __forceinline__ unsigned short f2bf16(float v) {
    return (unsigned short)pack2bf(v, v);   // single HW cvt, take low half
}
static __device__ __forceinline__ float bf2f_lo(unsigned u) { return __uint_as_float(u << 16); }
static __device__ __forceinline__ float bf2f_hi(unsigned u) { return __uint_as_float(u & 0xffff0000u); }

// ---------- CSR build ----------
__global__ void hist_kernel(const int* __restrict__ dst, unsigned* __restrict__ deg, int E) {
    int e = blockIdx.x * 256 + threadIdx.x;
    if (e < E) atomicAdd(&deg[dst[e]], 1u);
}

__global__ __launch_bounds__(256) void scan_partial(const unsigned* __restrict__ deg,
        unsigned* __restrict__ off, unsigned* __restrict__ bsum, int N) {
    int t = threadIdx.x;
    int base = blockIdx.x * 2048 + t * 8;
    unsigned v[8]; unsigned run = 0;
#pragma unroll
    for (int i = 0; i < 8; i++) {
        int g = base + i;
        unsigned d = (g < N) ? deg[g] : 0u;
        v[i] = run; run += d;
    }
    __shared__ unsigned s[256];
    s[t] = run; __syncthreads();
    for (int o2 = 1; o2 < 256; o2 <<= 1) {
        unsigned x = (t >= o2) ? s[t - o2] : 0u;
        __syncthreads();
        s[t] += x;
        __syncthreads();
    }
    unsigned texcl = (t > 0) ? s[t - 1] : 0u;
    if (t == 255) bsum[blockIdx.x] = s[255];
#pragma unroll
    for (int i = 0; i < 8; i++) {
        int g = base + i;
        if (g < N) off[g] = texcl + v[i];
    }
}

__global__ void scan_bsum(unsigned* bsum, int B) {   // B <= 64, single wave inclusive
    int t = threadIdx.x;
    unsigned v = (t < B) ? bsum[t] : 0u;
    for (int o = 1; o < 64; o <<= 1) {
        unsigned x = __shfl_up(v, o);
        if (t >= o) v += x;
    }
    if (t < B) bsum[t] = v;
}

__global__ void scan_add(unsigned* __restrict__ off, const unsigned* __restrict__ bsum, int N) {
    int g = blockIdx.x * 256 + threadIdx.x;
    if (g >= N) return;
    int blk = g >> 11;
    if (blk > 0) off[g] += bsum[blk - 1];
}

// fills: csrS[pos]=src, csrD[pos]=dst, csrE[pos]=edge id
__global__ void csr_fill(const int* __restrict__ src, const int* __restrict__ dst,
                         const unsigned* __restrict__ off, unsigned* __restrict__ cur,
                         int* __restrict__ csrS, int* __restrict__ csrD,
                         int* __restrict__ csrE, int E) {
    int e = blockIdx.x * 256 + threadIdx.x;
    if (e >= E) return;
    int d = dst[e];
    unsigned p = off[d] + atomicAdd(&cur[d], 1u);
    csrS[p] = src[e];
    csrD[p] = d;
    csrE[p] = e;
}

// ---------- node projection (writes bf16 h) ----------
__global__ void node_proj_kernel(const float* __restrict__ x, const float* __restrict__ W,
                                 const float* __restrict__ b, unsigned short* __restrict__ hbf, int N) {
    int i = blockIdx.x * 256 + threadIdx.x;   // over N*64, 2 cols/thread
    if (i >= N * 64) return;
    int n = i >> 6, f2 = (i & 63) * 2;
    float a0 = b[f2], a1 = b[f2 + 1];
#pragma unroll
    for (int k = 0; k < 5; k++) {
        float xv = x[n * 5 + k];
        a0 = fmaf(xv, W[k * HID + f2], a0);
        a1 = fmaf(xv, W[k * HID + f2 + 1], a1);
    }
    *(unsigned*)&hbf[(size_t)n * HID + f2] = pack2bf(a0, a1);
}

// ---------- merged weight prep ----------
__global__ void prep_weights(const float* __restrict__ W1, const float* __restrict__ W2,
                             const float* __restrict__ Wl, const float* __restrict__ Wr,
                             unsigned short* __restrict__ W1T, unsigned short* __restrict__ W2T,
                             unsigned short* __restrict__ WST) {
    int i = blockIdx.x * 256 + threadIdx.x;
    if (i < 128 * K1) {
        int n = i / K1, k = i - n * K1;
        W1T[i] = (k < 268) ? f2bf16(W1[k * HID + n]) : (unsigned short)0;
        return;
    }
    int j = i - 128 * K1;
    if (j < 64 * HID) {
        int n = j >> 7, k = j & 127;
        W2T[j] = f2bf16(W2[k * 64 + n]);
        return;
    }
    int m = j - 64 * HID;
    if (m < 3 * 128 * 256) {
        int l = m >> 15, rem = m & 32767, n = rem >> 8, k = rem & 255;
        float v = (k < 128) ? Wl[l * 16384 + k * 128 + n] : Wr[l * 16384 + (k - 128) * 128 + n];
        WST[m] = f2bf16(v);
    }
}

// ---------- mean aggregation: 4 nodes per wave, 8 rows in flight per group ----------
__global__ __launch_bounds__(256) void agg_csr(const unsigned short* __restrict__ hbf,
        const int* __restrict__ csr, const unsigned* __restrict__ off,
        const unsigned* __restrict__ degu, unsigned short* __restrict__ mean_bf, int N) {
    const int wv = threadIdx.x >> 6, lane = threadIdx.x & 63;
    const int g = lane >> 4, c = lane & 15;
    const int n = (blockIdx.x * 4 + wv) * 4 + g;
    const int nc = n < N ? n : N - 1;
    const unsigned o = off[nc];
    const unsigned d = (n < N) ? degu[nc] : 0u;
    unsigned dmax = d;
    dmax = max(dmax, (unsigned)__shfl_xor((int)dmax, 16));
    dmax = max(dmax, (unsigned)__shfl_xor((int)dmax, 32));

    float acc[8] = {0.f, 0.f, 0.f, 0.f, 0.f, 0.f, 0.f, 0.f};
    for (unsigned i = 0; i < dmax; i += 8) {
        uint4 v[8];
#pragma unroll
        for (int j = 0; j < 8; j++) {
            unsigned p = (i + j < d) ? o + i + j : 0u;
            int s = csr[p];
            v[j] = *(const uint4*)&hbf[(size_t)s * HID + c * 8];
        }
#pragma unroll
        for (int j = 0; j < 8; j++) {
            if (i + j < d) {
                acc[0] += bf2f_lo(v[j].x); acc[1] += bf2f_hi(v[j].x);
                acc[2] += bf2f_lo(v[j].y); acc[3] += bf2f_hi(v[j].y);
                acc[4] += bf2f_lo(v[j].z); acc[5] += bf2f_hi(v[j].z);
                acc[6] += bf2f_lo(v[j].w); acc[7] += bf2f_hi(v[j].w);
            }
        }
    }
    if (n < N) {
        float inv = d ? 1.f / (float)d : 0.f;
        uint4 p;
        p.x = pack2bf(acc[0] * inv, acc[1] * inv);
        p.y = pack2bf(acc[2] * inv, acc[3] * inv);
        p.z = pack2bf(acc[4] * inv, acc[5] * inv);
        p.w = pack2bf(acc[6] * inv, acc[7] * inv);
        *(uint4*)&mean_bf[(size_t)n * HID + c * 8] = p;
    }
}

// ---------- SAGE layer: [N x 256] @ [256 x 128] + bias + LN + ReLU, bf16 h in-place ----------
__global__ __launch_bounds__(256) void sage_mfma(
    unsigned short* __restrict__ hbf, const unsigned short* __restrict__ mean_bf,
    const unsigned short* __restrict__ WT,    // [128 out][256 k] bf16 (k<128: Wl, else Wr)
    const float* __restrict__ bl, const float* __restrict__ g,
    const float* __restrict__ bet, int N) {
    const int t = threadIdx.x, wave = t >> 6, lane = t & 63;
    const int ln15 = lane & 15, quad = lane >> 4;
    const int blkBase = blockIdx.x * 128;

    short8 af[2][8];
#pragma unroll
    for (int tt = 0; tt < 2; tt++) {
        int m = blkBase + tt * 64 + wave * 16 + ln15;
        int mc = m < N ? m : N - 1;
#pragma unroll
        for (int kt = 0; kt < 4; kt++)
            af[tt][kt] = *(const short8*)&mean_bf[(size_t)mc * HID + kt * 32 + quad * 8];
#pragma unroll
        for (int kt = 0; kt < 4; kt++)
            af[tt][4 + kt] = *(const short8*)&hbf[(size_t)mc * HID + kt * 32 + quad * 8];
    }

    floatx4 acc[2][8];
#pragma unroll
    for (int nt = 0; nt < 8; nt++) {
        floatx4 a0 = {0.f, 0.f, 0.f, 0.f}, a1 = {0.f, 0.f, 0.f, 0.f};
#pragma unroll
        for (int kt = 0; kt < 8; kt++) {
            short8 b = *(const short8*)&WT[(nt * 16 + ln15) * 256 + kt * 32 + quad * 8];
            a0 = __builtin_amdgcn_mfma_f32_16x16x32_bf16(af[0][kt], b, a0, 0, 0, 0);
            a1 = __builtin_amdgcn_mfma_f32_16x16x32_bf16(af[1][kt], b, a1, 0, 0, 0);
        }
        acc[0][nt] = a0; acc[1][nt] = a1;
    }

    float blv[8], gv[8], bv[8];
#pragma unroll
    for (int nt = 0; nt < 8; nt++) {
        int col = nt * 16 + ln15;
        blv[nt] = bl[col]; gv[nt] = g[col]; bv[nt] = bet[col];
    }

#pragma unroll
    for (int tt = 0; tt < 2; tt++) {
#pragma unroll
        for (int r = 0; r < 4; r++) {
            float s = 0.f;
#pragma unroll
            for (int nt = 0; nt < 8; nt++) s += acc[tt][nt][r] + blv[nt];
            s += __shfl_xor(s, 1); s += __shfl_xor(s, 2);
            s += __shfl_xor(s, 4); s += __shfl_xor(s, 8);
            float mu = s * (1.f / 128.f);
            float q = 0.f;
#pragma unroll
            for (int nt = 0; nt < 8; nt++) { float c = acc[tt][nt][r] + blv[nt] - mu; q += c * c; }
            q += __shfl_xor(q, 1); q += __shfl_xor(q, 2);
            q += __shfl_xor(q, 4); q += __shfl_xor(q, 8);
            float rstd = rsqrtf(q * (1.f / 128.f) + 1e-5f);
            int node = blkBase + tt * 64 + wave * 16 + quad * 4 + r;
            if (node < N) {
#pragma unroll
                for (int nt = 0; nt < 8; nt++) {
                    float y = fmaxf((acc[tt][nt][r] + blv[nt] - mu) * rstd * gv[nt] + bv[nt], 0.f);
                    hbf[(size_t)node * HID + nt * 16 + ln15] = f2bf16(y);   // 2B store, no shfl
                }
            }
        }
    }
}

// ---------- P/Q: P = h@W1a (in-place over hbf), Q = h@W1b (over meanbf) ----------
// 128 nodes/block, 2 M-tiles/wave -> each B-frag load feeds 2 MFMAs.
__global__ __launch_bounds__(256) void pq_mfma(
    unsigned short* __restrict__ hbf, unsigned short* __restrict__ qbf,
    const unsigned short* __restrict__ W1T, int N) {
    const int t = threadIdx.x, wave = t >> 6, lane = t & 63;
    const int ln15 = lane & 15, quad = lane >> 4;
    const int blkBase = blockIdx.x * 128;

    short8 af[2][4];
#pragma unroll
    for (int tt = 0; tt < 2; tt++) {
        int m = blkBase + tt * 64 + wave * 16 + ln15;
        int mc = m < N ? m : N - 1;
#pragma unroll
        for (int kt = 0; kt < 4; kt++)
            af[tt][kt] = *(const short8*)&hbf[(size_t)mc * HID + kt * 32 + quad * 8];
    }

#pragma unroll
    for (int nt = 0; nt < 8; nt++) {
#pragma unroll
        for (int sel = 0; sel < 2; sel++) {
            floatx4 a0 = {0.f, 0.f, 0.f, 0.f}, a1 = {0.f, 0.f, 0.f, 0.f};
#pragma unroll
            for (int kt = 0; kt < 4; kt++) {
                short8 b = *(const short8*)&W1T[(size_t)(nt * 16 + ln15) * K1 + sel * 128 + kt * 32 + quad * 8];
                a0 = __builtin_amdgcn_mfma_f32_16x16x32_bf16(af[0][kt], b, a0, 0, 0, 0);
                a1 = __builtin_amdgcn_mfma_f32_16x16x32_bf16(af[1][kt], b, a1, 0, 0, 0);
            }
            unsigned short* outp = sel ? qbf : hbf;
            floatx4 aa[2] = {a0, a1};
#pragma unroll
            for (int tt = 0; tt < 2; tt++) {
#pragma unroll
                for (int r = 0; r < 4; r++) {
                    int node = blkBase + tt * 64 + wave * 16 + quad * 4 + r;
                    if (node < N)
                        outp[(size_t)node * HID + nt * 16 + ln15] = f2bf16(aa[tt][r]);
                }
            }
        }
    }
}

// ---------- edge MLP: z1 = relu(P[src]+Q[dst]+eattr@W1c+b1); 64 pos/block ----------
__global__ __launch_bounds__(256) void edge_mlp_mfma(
    const unsigned short* __restrict__ Pbf, const unsigned short* __restrict__ Qbf,
    const int* __restrict__ csrS, const int* __restrict__ csrD, const int* __restrict__ csrE,
    const float* __restrict__ eattr,
    const unsigned short* __restrict__ W1T, const float* __restrict__ b1,
    const unsigned short* __restrict__ W2T, const float* __restrict__ b2,
    const float* __restrict__ W3, const float* __restrict__ b3,
    float* __restrict__ out, int E)
{
    const int t = threadIdx.x;
    const int eBase = blockIdx.x * ET;
    __shared__ __align__(16) char smem[ET * Z2S * 4];   // 17664 B: S bf16 [64][136] / z2 fp32 [64][69]
    unsigned short* sS = (unsigned short*)smem;
    float* sZ2 = (float*)smem;

    const int wave = t >> 6, lane = t & 63;
    const int ln15 = lane & 15, quad = lane >> 4;
    const int rowb = wave * 16 + ln15;
    const int pos = eBase + rowb;
    const int pc = pos < E ? pos : E - 1;
    const int rs = csrS[pc], rd = csrD[pc], re = csrE[pc];

    short8 pf[4], qf[4];
#pragma unroll
    for (int kt = 0; kt < 4; kt++)
        pf[kt] = *(const short8*)&Pbf[(size_t)rs * HID + kt * 32 + quad * 8];
#pragma unroll
    for (int kt = 0; kt < 4; kt++)
        qf[kt] = *(const short8*)&Qbf[(size_t)rd * HID + kt * 32 + quad * 8];

    short8 ef = {0, 0, 0, 0, 0, 0, 0, 0};
    if (pos < E) {
        const float* ep = eattr + (size_t)re * 12;
        if (quad == 0) {
            float4 p0 = *(const float4*)ep, p1 = *(const float4*)(ep + 4);
            unsigned* eu = (unsigned*)&ef;
            eu[0] = pack2bf(p0.x, p0.y); eu[1] = pack2bf(p0.z, p0.w);
            eu[2] = pack2bf(p1.x, p1.y); eu[3] = pack2bf(p1.z, p1.w);
        } else if (quad == 1) {
            float4 p2 = *(const float4*)(ep + 8);
            unsigned* eu = (unsigned*)&ef;
            eu[0] = pack2bf(p2.x, p2.y); eu[1] = pack2bf(p2.z, p2.w);
        }
    }

    // S = eattr @ W1c + b1 (the K=[256,288) slice of W1T) -> LDS C-layout, 2B stores
#pragma unroll
    for (int nt = 0; nt < 8; nt++) {
        floatx4 sa = {0.f, 0.f, 0.f, 0.f};
        short8 b = *(const short8*)&W1T[(size_t)(nt * 16 + ln15) * K1 + 256 + quad * 8];
        sa = __builtin_amdgcn_mfma_f32_16x16x32_bf16(ef, b, sa, 0, 0, 0);
        float bias = b1[nt * 16 + ln15];
#pragma unroll
        for (int r = 0; r < 4; r++) {
            int row = wave * 16 + quad * 4 + r;
            sS[row * Z1S + nt * 16 + ln15] = f2bf16(sa[r] + bias);   // no relu yet
        }
    }
    __syncthreads();

    // z1 = relu(P + Q + S) in registers (A-layout), pairwise with HW packed cvt
    short8 zf[4];
#pragma unroll
    for (int kt = 0; kt < 4; kt++) {
        short8 s8 = *(const short8*)&sS[rowb * Z1S + kt * 32 + quad * 8];
#pragma unroll
        for (int w = 0; w < 4; w++) {
            unsigned up = ((unsigned*)&pf[kt])[w];
            unsigned uq = ((unsigned*)&qf[kt])[w];
            unsigned us = ((unsigned*)&s8)[w];
            float lo = bf2f_lo(up) + bf2f_lo(uq) + bf2f_lo(us);
            float hi = bf2f_hi(up) + bf2f_hi(uq) + bf2f_hi(us);
            ((unsigned*)&zf[kt])[w] = pack2bf(fmaxf(lo, 0.f), fmaxf(hi, 0.f));
        }
    }
    __syncthreads();    // all S reads done before z2 overlays

    // layer 2: [64 x 128] -> [64 x 64]
#pragma unroll
    for (int nt = 0; nt < 4; nt++) {
        floatx4 a = {0.f, 0.f, 0.f, 0.f};
#pragma unroll
        for (int kt = 0; kt < 4; kt++) {
            short8 b = *(const short8*)&W2T[(nt * 16 + ln15) * HID + kt * 32 + quad * 8];
            a = __builtin_amdgcn_mfma_f32_16x16x32_bf16(zf[kt], b, a, 0, 0, 0);
        }
        float bias = b2[nt * 16 + ln15];
#pragma unroll
        for (int r = 0; r < 4; r++) {
            int row = wave * 16 + quad * 4 + r;
            sZ2[row * Z2S + nt * 16 + ln15] = fmaxf(a[r] + bias, 0.f);
        }
    }
    __syncthreads();

    // layer 3 + softplus (fp32), one thread per position; scattered write to out[edge]
    if (t < ET) {
        int p = eBase + t;
        if (p < E) {
            float a3 = b3[0];
            const float* z2 = sZ2 + t * Z2S;
#pragma unroll
            for (int k = 0; k < 64; k++) a3 = fmaf(z2[k], W3[k], a3);
            out[csrE[p]] = fmaxf(a3, 0.f) + log1pf(expf(-fabsf(a3)));
        }
    }
}

extern "C" void kernel_launch(void* const* d_in, const int* in_sizes, int n_in,
                              void* d_out, int out_size, void* d_ws, size_t ws_size,
                              hipStream_t stream) {
    const float* x       = (const float*)d_in[0];
    const int*   ei      = (const int*)d_in[1];
    const float* eattr   = (const float*)d_in[2];
    const float* node_W  = (const float*)d_in[3];
    const float* node_b  = (const float*)d_in[4];
    const float* sage_Wl = (const float*)d_in[5];
    const float* sage_bl = (const float*)d_in[6];
    const float* sage_Wr = (const float*)d_in[7];
    const float* ln_g    = (const float*)d_in[8];
    const float* ln_b    = (const float*)d_in[9];
    const float* W1 = (const float*)d_in[10];
    const float* b1 = (const float*)d_in[11];
    const float* W2 = (const float*)d_in[12];
    const float* b2 = (const float*)d_in[13];
    const float* W3 = (const float*)d_in[14];
    const float* b3 = (const float*)d_in[15];
    float* out = (float*)d_out;

    const int N = in_sizes[0] / 5;
    const int E = in_sizes[1] / 2;
    const int* src  = ei;
    const int* dstp = ei + E;

    char* ws = (char*)d_ws;
    size_t cur_off = 0;
    auto alloc = [&](size_t bytes) { size_t p = cur_off; cur_off = (cur_off + bytes + 255) & ~(size_t)255; return p; };
    unsigned short* hbf    = (unsigned short*)(ws + alloc((size_t)N * HID * 2));  // h, later P
    unsigned short* meanbf = (unsigned short*)(ws + alloc((size_t)N * HID * 2));  // mean, later Q
    int*            csrS   = (int*)(ws + alloc((size_t)E * 4));
    int*            csrD   = (int*)(ws + alloc((size_t)E * 4));
    int*            csrE   = (int*)(ws + alloc((size_t)E * 4));
    unsigned*       degu   = (unsigned*)(ws + alloc((size_t)N * 4));
    unsigned*       curp   = (unsigned*)(ws + alloc((size_t)N * 4));
    unsigned*       offs   = (unsigned*)(ws + alloc((size_t)N * 4));
    unsigned*       bsum   = (unsigned*)(ws + alloc(64 * 4));
    unsigned short* W1T    = (unsigned short*)(ws + alloc(128 * K1 * 2));
    unsigned short* W2T    = (unsigned short*)(ws + alloc(64 * HID * 2));
    unsigned short* WST    = (unsigned short*)(ws + alloc(3 * 128 * 256 * 2));

    hipMemsetAsync(degu, 0, (size_t)N * sizeof(unsigned), stream);
    hipMemsetAsync(curp, 0, (size_t)N * sizeof(unsigned), stream);
    hist_kernel<<<(E + 255) / 256, 256, 0, stream>>>(dstp, degu, E);
    int NB = (N + 2047) / 2048;   // 49 for N=100000, fits the 64-lane bsum scan
    scan_partial<<<NB, 256, 0, stream>>>(degu, offs, bsum, N);
    scan_bsum<<<1, 64, 0, stream>>>(bsum, NB);
    scan_add<<<(N + 255) / 256, 256, 0, stream>>>(offs, bsum, N);
    csr_fill<<<(E + 255) / 256, 256, 0, stream>>>(src, dstp, offs, curp, csrS, csrD, csrE, E);

    int prepTotal = 128 * K1 + 64 * HID + 3 * 128 * 256;
    prep_weights<<<(prepTotal + 255) / 256, 256, 0, stream>>>(W1, W2, sage_Wl, sage_Wr, W1T, W2T, WST);

    node_proj_kernel<<<(N * 64 + 255) / 256, 256, 0, stream>>>(x, node_W, node_b, hbf, N);

    for (int l = 0; l < 3; l++) {
        agg_csr<<<(N + 15) / 16, 256, 0, stream>>>(hbf, csrS, offs, degu, meanbf, N);
        sage_mfma<<<(N + 127) / 128, 256, 0, stream>>>(
            hbf, meanbf, WST + (size_t)l * 128 * 256,
            sage_bl + (size_t)l * HID, ln_g + (size_t)l * HID, ln_b + (size_t)l * HID, N);
    }

    // P = h@W1a (in-place over hbf), Q = h@W1b (over meanbf)
    pq_mfma<<<(N + 127) / 128, 256, 0, stream>>>(hbf, meanbf, W1T, N);

    edge_mlp_mfma<<<(E + ET - 1) / ET, 256, 0, stream>>>(
        hbf, meanbf, csrS, csrD, csrE, eattr, W1T, b1, W2T, b2, W3, b3, out, E);
}

// Round 10
// 652.668 us; speedup vs baseline: 1.1475x; 1.0266x over previous
//
#include <hip/hip_runtime.h>
#include <hip/hip_bf16.h>
#include <math.h>

#define HID 128
#define ET  64          // edges per block (edge MLP), 1 M-tile per wave
#define K1  288         // padded K for layer 1 (268 -> 9*32)
#define Z1S 136         // S LDS stride in bf16
#define Z2S 69          // z2 LDS stride in fp32
#define SMS 136         // sage_pq h-transpose LDS stride in bf16

typedef __attribute__((ext_vector_type(8))) short short8;   // 8 bf16 = 4 VGPRs
typedef __attribute__((ext_vector_type(4))) float floatx4;  // MFMA accumulator

// HW packed convert: v_cvt_pk_bf16_f32 (RNE), lo -> low 16 bits
static __device__ __forceinline__ unsigned pack2bf(float lo, float hi) {
    __hip_bfloat162 v = __float22bfloat162_rn(float2{lo, hi});
    union { __hip_bfloat162 b; unsigned u; } cv; cv.b = v; return cv.u;
}
static __device__ __forceinline__ unsigned short f2bf16(float v) {
    return (unsigned short)pack2bf(v, v);
}
static __device__ __forceinline__ float bf2f_lo(unsigned u) { return __uint_as_float(u << 16); }
static __device__ __forceinline__ float bf2f_hi(unsigned u) { return __uint_as_float(u & 0xffff0000u); }

// ---------- CSR build ----------
__global__ void hist_kernel(const int* __restrict__ dst, unsigned* __restrict__ deg, int E) {
    int e = blockIdx.x * 256 + threadIdx.x;
    if (e < E) atomicAdd(&deg[dst[e]], 1u);
}

__global__ __launch_bounds__(256) void scan_partial(const unsigned* __restrict__ deg,
        unsigned* __restrict__ off, unsigned* __restrict__ bsum, int N) {
    int t = threadIdx.x;
    int base = blockIdx.x * 2048 + t * 8;
    unsigned v[8]; unsigned run = 0;
#pragma unroll
    for (int i = 0; i < 8; i++) {
        int g = base + i;
        unsigned d = (g < N) ? deg[g] : 0u;
        v[i] = run; run += d;
    }
    __shared__ unsigned s[256];
    s[t] = run; __syncthreads();
    for (int o2 = 1; o2 < 256; o2 <<= 1) {
        unsigned x = (t >= o2) ? s[t - o2] : 0u;
        __syncthreads();
        s[t] += x;
        __syncthreads();
    }
    unsigned texcl = (t > 0) ? s[t - 1] : 0u;
    if (t == 255) bsum[blockIdx.x] = s[255];
#pragma unroll
    for (int i = 0; i < 8; i++) {
        int g = base + i;
        if (g < N) off[g] = texcl + v[i];
    }
}

__global__ void scan_bsum(unsigned* bsum, int B) {   // B <= 64, single wave inclusive
    int t = threadIdx.x;
    unsigned v = (t < B) ? bsum[t] : 0u;
    for (int o = 1; o < 64; o <<= 1) {
        unsigned x = __shfl_up(v, o);
        if (t >= o) v += x;
    }
    if (t < B) bsum[t] = v;
}

__global__ void scan_add(unsigned* __restrict__ off, const unsigned* __restrict__ bsum,
                         unsigned* __restrict__ cur, int N) {
    int g = blockIdx.x * 256 + threadIdx.x;
    if (g >= N) return;
    cur[g] = 0u;                 // folded curp reset (one fewer memset dispatch)
    int blk = g >> 11;
    if (blk > 0) off[g] += bsum[blk - 1];
}

// fills: csrS/csrD/csrE + eattr copied into CSR order as bf16 (24 B/edge)
__global__ void csr_fill(const int* __restrict__ src, const int* __restrict__ dst,
                         const float* __restrict__ eattr,
                         const unsigned* __restrict__ off, unsigned* __restrict__ cur,
                         int* __restrict__ csrS, int* __restrict__ csrD,
                         int* __restrict__ csrE, unsigned short* __restrict__ eattrP, int E) {
    int e = blockIdx.x * 256 + threadIdx.x;
    if (e >= E) return;
    int d = dst[e];
    unsigned p = off[d] + atomicAdd(&cur[d], 1u);
    csrS[p] = src[e];
    csrD[p] = d;
    csrE[p] = e;
    const float* ep = eattr + (size_t)e * 12;       // 48 B, 16-aligned: coalesced read
    float4 v0 = *(const float4*)ep;
    float4 v1 = *(const float4*)(ep + 4);
    float4 v2 = *(const float4*)(ep + 8);
    unsigned* op = (unsigned*)(eattrP + (size_t)p * 12);  // 4-aligned scatter write
    op[0] = pack2bf(v0.x, v0.y); op[1] = pack2bf(v0.z, v0.w);
    op[2] = pack2bf(v1.x, v1.y); op[3] = pack2bf(v1.z, v1.w);
    op[4] = pack2bf(v2.x, v2.y); op[5] = pack2bf(v2.z, v2.w);
}

// ---------- node projection (writes bf16 h) ----------
__global__ void node_proj_kernel(const float* __restrict__ x, const float* __restrict__ W,
                                 const float* __restrict__ b, unsigned short* __restrict__ hbf, int N) {
    int i = blockIdx.x * 256 + threadIdx.x;   // over N*64, 2 cols/thread
    if (i >= N * 64) return;
    int n = i >> 6, f2 = (i & 63) * 2;
    float a0 = b[f2], a1 = b[f2 + 1];
#pragma unroll
    for (int k = 0; k < 5; k++) {
        float xv = x[n * 5 + k];
        a0 = fmaf(xv, W[k * HID + f2], a0);
        a1 = fmaf(xv, W[k * HID + f2 + 1], a1);
    }
    *(unsigned*)&hbf[(size_t)n * HID + f2] = pack2bf(a0, a1);
}

// ---------- merged weight prep ----------
__global__ void prep_weights(const float* __restrict__ W1, const float* __restrict__ W2,
                             const float* __restrict__ Wl, const float* __restrict__ Wr,
                             unsigned short* __restrict__ W1T, unsigned short* __restrict__ W2T,
                             unsigned short* __restrict__ WST) {
    int i = blockIdx.x * 256 + threadIdx.x;
    if (i < 128 * K1) {
        int n = i / K1, k = i - n * K1;
        W1T[i] = (k < 268) ? f2bf16(W1[k * HID + n]) : (unsigned short)0;
        return;
    }
    int j = i - 128 * K1;
    if (j < 64 * HID) {
        int n = j >> 7, k = j & 127;
        W2T[j] = f2bf16(W2[k * 64 + n]);
        return;
    }
    int m = j - 64 * HID;
    if (m < 3 * 128 * 256) {
        int l = m >> 15, rem = m & 32767, n = rem >> 8, k = rem & 255;
        float v = (k < 128) ? Wl[l * 16384 + k * 128 + n] : Wr[l * 16384 + (k - 128) * 128 + n];
        WST[m] = f2bf16(v);
    }
}

// ---------- mean aggregation: 4 nodes per wave, 8 rows in flight per group ----------
__global__ __launch_bounds__(256) void agg_csr(const unsigned short* __restrict__ hbf,
        const int* __restrict__ csr, const unsigned* __restrict__ off,
        const unsigned* __restrict__ degu, unsigned short* __restrict__ mean_bf, int N) {
    const int wv = threadIdx.x >> 6, lane = threadIdx.x & 63;
    const int g = lane >> 4, c = lane & 15;
    const int n = (blockIdx.x * 4 + wv) * 4 + g;
    const int nc = n < N ? n : N - 1;
    const unsigned o = off[nc];
    const unsigned d = (n < N) ? degu[nc] : 0u;
    unsigned dmax = d;
    dmax = max(dmax, (unsigned)__shfl_xor((int)dmax, 16));
    dmax = max(dmax, (unsigned)__shfl_xor((int)dmax, 32));

    float acc[8] = {0.f, 0.f, 0.f, 0.f, 0.f, 0.f, 0.f, 0.f};
    for (unsigned i = 0; i < dmax; i += 8) {
        uint4 v[8];
#pragma unroll
        for (int j = 0; j < 8; j++) {
            unsigned p = (i + j < d) ? o + i + j : 0u;
            int s = csr[p];
            v[j] = *(const uint4*)&hbf[(size_t)s * HID + c * 8];
        }
#pragma unroll
        for (int j = 0; j < 8; j++) {
            if (i + j < d) {
                acc[0] += bf2f_lo(v[j].x); acc[1] += bf2f_hi(v[j].x);
                acc[2] += bf2f_lo(v[j].y); acc[3] += bf2f_hi(v[j].y);
                acc[4] += bf2f_lo(v[j].z); acc[5] += bf2f_hi(v[j].z);
                acc[6] += bf2f_lo(v[j].w); acc[7] += bf2f_hi(v[j].w);
            }
        }
    }
    if (n < N) {
        float inv = d ? 1.f / (float)d : 0.f;
        uint4 p;
        p.x = pack2bf(acc[0] * inv, acc[1] * inv);
        p.y = pack2bf(acc[2] * inv, acc[3] * inv);
        p.z = pack2bf(acc[4] * inv, acc[5] * inv);
        p.w = pack2bf(acc[6] * inv, acc[7] * inv);
        *(uint4*)&mean_bf[(size_t)n * HID + c * 8] = p;
    }
}

// ---------- SAGE layer (layers 0,1): h in-place, no LDS ----------
__global__ __launch_bounds__(256) void sage_mfma(
    unsigned short* __restrict__ hbf, const unsigned short* __restrict__ mean_bf,
    const unsigned short* __restrict__ WT,
    const float* __restrict__ bl, const float* __restrict__ g,
    const float* __restrict__ bet, int N) {
    const int t = threadIdx.x, wave = t >> 6, lane = t & 63;
    const int ln15 = lane & 15, quad = lane >> 4;
    const int blkBase = blockIdx.x * 128;

    short8 af[2][8];
#pragma unroll
    for (int tt = 0; tt < 2; tt++) {
        int m = blkBase + tt * 64 + wave * 16 + ln15;
        int mc = m < N ? m : N - 1;
#pragma unroll
        for (int kt = 0; kt < 4; kt++)
            af[tt][kt] = *(const short8*)&mean_bf[(size_t)mc * HID + kt * 32 + quad * 8];
#pragma unroll
        for (int kt = 0; kt < 4; kt++)
            af[tt][4 + kt] = *(const short8*)&hbf[(size_t)mc * HID + kt * 32 + quad * 8];
    }

    floatx4 acc[2][8];
#pragma unroll
    for (int nt = 0; nt < 8; nt++) {
        floatx4 a0 = {0.f, 0.f, 0.f, 0.f}, a1 = {0.f, 0.f, 0.f, 0.f};
#pragma unroll
        for (int kt = 0; kt < 8; kt++) {
            short8 b = *(const short8*)&WT[(nt * 16 + ln15) * 256 + kt * 32 + quad * 8];
            a0 = __builtin_amdgcn_mfma_f32_16x16x32_bf16(af[0][kt], b, a0, 0, 0, 0);
            a1 = __builtin_amdgcn_mfma_f32_16x16x32_bf16(af[1][kt], b, a1, 0, 0, 0);
        }
        acc[0][nt] = a0; acc[1][nt] = a1;
    }

    float blv[8], gv[8], bv[8];
#pragma unroll
    for (int nt = 0; nt < 8; nt++) {
        int col = nt * 16 + ln15;
        blv[nt] = bl[col]; gv[nt] = g[col]; bv[nt] = bet[col];
    }

#pragma unroll
    for (int tt = 0; tt < 2; tt++) {
#pragma unroll
        for (int r = 0; r < 4; r++) {
            float s = 0.f;
#pragma unroll
            for (int nt = 0; nt < 8; nt++) s += acc[tt][nt][r] + blv[nt];
            s += __shfl_xor(s, 1); s += __shfl_xor(s, 2);
            s += __shfl_xor(s, 4); s += __shfl_xor(s, 8);
            float mu = s * (1.f / 128.f);
            float q = 0.f;
#pragma unroll
            for (int nt = 0; nt < 8; nt++) { float c = acc[tt][nt][r] + blv[nt] - mu; q += c * c; }
            q += __shfl_xor(q, 1); q += __shfl_xor(q, 2);
            q += __shfl_xor(q, 4); q += __shfl_xor(q, 8);
            float rstd = rsqrtf(q * (1.f / 128.f) + 1e-5f);
            int node = blkBase + tt * 64 + wave * 16 + quad * 4 + r;
            if (node < N) {
#pragma unroll
                for (int nt = 0; nt < 8; nt++) {
                    float y = fmaxf((acc[tt][nt][r] + blv[nt] - mu) * rstd * gv[nt] + bv[nt], 0.f);
                    hbf[(size_t)node * HID + nt * 16 + ln15] = f2bf16(y);
                }
            }
        }
    }
}

// ---------- SAGE final layer + P/Q epilogue: writes P (over hbf) and Q (over meanbf) ----------
__global__ __launch_bounds__(256) void sage_pq_mfma(
    unsigned short* __restrict__ hbf, unsigned short* __restrict__ mean_bf,
    const unsigned short* __restrict__ WT,
    const float* __restrict__ bl, const float* __restrict__ g,
    const float* __restrict__ bet, const unsigned short* __restrict__ W1T, int N) {
    __shared__ __align__(16) unsigned short sh[128 * SMS];   // 34816 B h-transpose
    const int t = threadIdx.x, wave = t >> 6, lane = t & 63;
    const int ln15 = lane & 15, quad = lane >> 4;
    const int blkBase = blockIdx.x * 128;

    short8 af[2][8];
#pragma unroll
    for (int tt = 0; tt < 2; tt++) {
        int m = blkBase + tt * 64 + wave * 16 + ln15;
        int mc = m < N ? m : N - 1;
#pragma unroll
        for (int kt = 0; kt < 4; kt++)
            af[tt][kt] = *(const short8*)&mean_bf[(size_t)mc * HID + kt * 32 + quad * 8];
#pragma unroll
        for (int kt = 0; kt < 4; kt++)
            af[tt][4 + kt] = *(const short8*)&hbf[(size_t)mc * HID + kt * 32 + quad * 8];
    }

    floatx4 acc[2][8];
#pragma unroll
    for (int nt = 0; nt < 8; nt++) {
        floatx4 a0 = {0.f, 0.f, 0.f, 0.f}, a1 = {0.f, 0.f, 0.f, 0.f};
#pragma unroll
        for (int kt = 0; kt < 8; kt++) {
            short8 b = *(const short8*)&WT[(nt * 16 + ln15) * 256 + kt * 32 + quad * 8];
            a0 = __builtin_amdgcn_mfma_f32_16x16x32_bf16(af[0][kt], b, a0, 0, 0, 0);
            a1 = __builtin_amdgcn_mfma_f32_16x16x32_bf16(af[1][kt], b, a1, 0, 0, 0);
        }
        acc[0][nt] = a0; acc[1][nt] = a1;
    }

    float blv[8], gv[8], bv[8];
#pragma unroll
    for (int nt = 0; nt < 8; nt++) {
        int col = nt * 16 + ln15;
        blv[nt] = bl[col]; gv[nt] = g[col]; bv[nt] = bet[col];
    }

    // LN + ReLU -> LDS transpose (write all 128 rows; clamped rows harmless, discarded on store)
#pragma unroll
    for (int tt = 0; tt < 2; tt++) {
#pragma unroll
        for (int r = 0; r < 4; r++) {
            float s = 0.f;
#pragma unroll
            for (int nt = 0; nt < 8; nt++) s += acc[tt][nt][r] + blv[nt];
            s += __shfl_xor(s, 1); s += __shfl_xor(s, 2);
            s += __shfl_xor(s, 4); s += __shfl_xor(s, 8);
            float mu = s * (1.f / 128.f);
            float q = 0.f;
#pragma unroll
            for (int nt = 0; nt < 8; nt++) { float c = acc[tt][nt][r] + blv[nt] - mu; q += c * c; }
            q += __shfl_xor(q, 1); q += __shfl_xor(q, 2);
            q += __shfl_xor(q, 4); q += __shfl_xor(q, 8);
            float rstd = rsqrtf(q * (1.f / 128.f) + 1e-5f);
            int row = tt * 64 + wave * 16 + quad * 4 + r;
#pragma unroll
            for (int nt = 0; nt < 8; nt++) {
                float y = fmaxf((acc[tt][nt][r] + blv[nt] - mu) * rstd * gv[nt] + bv[nt], 0.f);
                sh[row * SMS + nt * 16 + ln15] = f2bf16(y);
            }
        }
    }
    __syncthreads();   // also guarantees all global af reads complete before P/Q overwrite

    short8 hf[2][4];
#pragma unroll
    for (int tt = 0; tt < 2; tt++)
#pragma unroll
        for (int kt = 0; kt < 4; kt++)
            hf[tt][kt] = *(const short8*)&sh[(tt * 64 + wave * 16 + ln15) * SMS + kt * 32 + quad * 8];

#pragma unroll
    for (int nt = 0; nt < 8; nt++) {
#pragma unroll
        for (int sel = 0; sel < 2; sel++) {
            floatx4 a0 = {0.f, 0.f, 0.f, 0.f}, a1 = {0.f, 0.f, 0.f, 0.f};
#pragma unroll
            for (int kt = 0; kt < 4; kt++) {
                short8 b = *(const short8*)&W1T[(size_t)(nt * 16 + ln15) * K1 + sel * 128 + kt * 32 + quad * 8];
                a0 = __builtin_amdgcn_mfma_f32_16x16x32_bf16(hf[0][kt], b, a0, 0, 0, 0);
                a1 = __builtin_amdgcn_mfma_f32_16x16x32_bf16(hf[1][kt], b, a1, 0, 0, 0);
            }
            unsigned short* outp = sel ? mean_bf : hbf;
            floatx4 aa[2] = {a0, a1};
#pragma unroll
            for (int tt = 0; tt < 2; tt++) {
#pragma unroll
                for (int r = 0; r < 4; r++) {
                    int node = blkBase + tt * 64 + wave * 16 + quad * 4 + r;
                    if (node < N)
                        outp[(size_t)node * HID + nt * 16 + ln15] = f2bf16(aa[tt][r]);
                }
            }
        }
    }
}

// ---------- edge MLP: z1 = relu(P[src]+Q[dst]+eattrP@W1c+b1); 64 pos/block ----------
__global__ __launch_bounds__(256) void edge_mlp_mfma(
    const unsigned short* __restrict__ Pbf, const unsigned short* __restrict__ Qbf,
    const int* __restrict__ csrS, const int* __restrict__ csrD, const int* __restrict__ csrE,
    const unsigned short* __restrict__ eattrP,
    const unsigned short* __restrict__ W1T, const float* __restrict__ b1,
    const unsigned short* __restrict__ W2T, const float* __restrict__ b2,
    const float* __restrict__ W3, const float* __restrict__ b3,
    float* __restrict__ out, int E)
{
    const int t = threadIdx.x;
    const int eBase = blockIdx.x * ET;
    __shared__ __align__(16) char smem[ET * Z2S * 4];   // 17664 B: S bf16 [64][136] / z2 fp32 [64][69]
    unsigned short* sS = (unsigned short*)smem;
    float* sZ2 = (float*)smem;

    const int wave = t >> 6, lane = t & 63;
    const int ln15 = lane & 15, quad = lane >> 4;
    const int rowb = wave * 16 + ln15;
    const int pos = eBase + rowb;
    const int pc = pos < E ? pos : E - 1;
    const int rs = csrS[pc], rd = csrD[pc];

    short8 pf[4], qf[4];
#pragma unroll
    for (int kt = 0; kt < 4; kt++)
        pf[kt] = *(const short8*)&Pbf[(size_t)rs * HID + kt * 32 + quad * 8];
#pragma unroll
    for (int kt = 0; kt < 4; kt++)
        qf[kt] = *(const short8*)&Qbf[(size_t)rd * HID + kt * 32 + quad * 8];

    // eattr in CSR order, bf16, contiguous: 24 B/edge
    short8 ef = {0, 0, 0, 0, 0, 0, 0, 0};
    {
        const unsigned* ep = (const unsigned*)(eattrP + (size_t)pc * 12);
        unsigned* eu = (unsigned*)&ef;
        if (quad == 0) {
            eu[0] = ep[0]; eu[1] = ep[1]; eu[2] = ep[2]; eu[3] = ep[3];
        } else if (quad == 1) {
            eu[0] = ep[4]; eu[1] = ep[5];
        }
    }

    // S = eattr @ W1c + b1 (K=[256,288) slice of W1T) -> LDS C-layout, 2B stores
#pragma unroll
    for (int nt = 0; nt < 8; nt++) {
        floatx4 sa = {0.f, 0.f, 0.f, 0.f};
        short8 b = *(const short8*)&W1T[(size_t)(nt * 16 + ln15) * K1 + 256 + quad * 8];
        sa = __builtin_amdgcn_mfma_f32_16x16x32_bf16(ef, b, sa, 0, 0, 0);
        float bias = b1[nt * 16 + ln15];
#pragma unroll
        for (int r = 0; r < 4; r++) {
            int row = wave * 16 + quad * 4 + r;
            sS[row * Z1S + nt * 16 + ln15] = f2bf16(sa[r] + bias);
        }
    }
    __syncthreads();

    // z1 = relu(P + Q + S), pairwise with HW packed cvt
    short8 zf[4];
#pragma unroll
    for (int kt = 0; kt < 4; kt++) {
        short8 s8 = *(const short8*)&sS[rowb * Z1S + kt * 32 + quad * 8];
#pragma unroll
        for (int w = 0; w < 4; w++) {
            unsigned up = ((unsigned*)&pf[kt])[w];
            unsigned uq = ((unsigned*)&qf[kt])[w];
            unsigned us = ((unsigned*)&s8)[w];
            float lo = bf2f_lo(up) + bf2f_lo(uq) + bf2f_lo(us);
            float hi = bf2f_hi(up) + bf2f_hi(uq) + bf2f_hi(us);
            ((unsigned*)&zf[kt])[w] = pack2bf(fmaxf(lo, 0.f), fmaxf(hi, 0.f));
        }
    }
    __syncthreads();    // all S reads done before z2 overlays

    // layer 2: [64 x 128] -> [64 x 64]
#pragma unroll
    for (int nt = 0; nt < 4; nt++) {
        floatx4 a = {0.f, 0.f, 0.f, 0.f};
#pragma unroll
        for (int kt = 0; kt < 4; kt++) {
            short8 b = *(const short8*)&W2T[(nt * 16 + ln15) * HID + kt * 32 + quad * 8];
            a = __builtin_amdgcn_mfma_f32_16x16x32_bf16(zf[kt], b, a, 0, 0, 0);
        }
        float bias = b2[nt * 16 + ln15];
#pragma unroll
        for (int r = 0; r < 4; r++) {
            int row = wave * 16 + quad * 4 + r;
            sZ2[row * Z2S + nt * 16 + ln15] = fmaxf(a[r] + bias, 0.f);
        }
    }
    __syncthreads();

    // layer 3 + softplus (fp32), one thread per position; scattered write to out[edge]
    if (t < ET) {
        int p = eBase + t;
        if (p < E) {
            float a3 = b3[0];
            const float* z2 = sZ2 + t * Z2S;
#pragma unroll
            for (int k = 0; k < 64; k++) a3 = fmaf(z2[k], W3[k], a3);
            out[csrE[p]] = fmaxf(a3, 0.f) + log1pf(expf(-fabsf(a3)));
        }
    }
}

extern "C" void kernel_launch(void* const* d_in, const int* in_sizes, int n_in,
                              void* d_out, int out_size, void* d_ws, size_t ws_size,
                              hipStream_t stream) {
    const float* x       = (const float*)d_in[0];
    const int*   ei      = (const int*)d_in[1];
    const float* eattr   = (const float*)d_in[2];
    const float* node_W  = (const float*)d_in[3];
    const float* node_b  = (const float*)d_in[4];
    const float* sage_Wl = (const float*)d_in[5];
    const float* sage_bl = (const float*)d_in[6];
    const float* sage_Wr = (const float*)d_in[7];
    const float* ln_g    = (const float*)d_in[8];
    const float* ln_b    = (const float*)d_in[9];
    const float* W1 = (const float*)d_in[10];
    const float* b1 = (const float*)d_in[11];
    const float* W2 = (const float*)d_in[12];
    const float* b2 = (const float*)d_in[13];
    const float* W3 = (const float*)d_in[14];
    const float* b3 = (const float*)d_in[15];
    float* out = (float*)d_out;

    const int N = in_sizes[0] / 5;
    const int E = in_sizes[1] / 2;
    const int* src  = ei;
    const int* dstp = ei + E;

    char* ws = (char*)d_ws;
    size_t cur_off = 0;
    auto alloc = [&](size_t bytes) { size_t p = cur_off; cur_off = (cur_off + bytes + 255) & ~(size_t)255; return p; };
    unsigned short* hbf    = (unsigned short*)(ws + alloc((size_t)N * HID * 2));  // h, later P
    unsigned short* meanbf = (unsigned short*)(ws + alloc((size_t)N * HID * 2));  // mean, later Q
    int*            csrS   = (int*)(ws + alloc((size_t)E * 4));
    int*            csrD   = (int*)(ws + alloc((size_t)E * 4));
    int*            csrE   = (int*)(ws + alloc((size_t)E * 4));
    unsigned short* eattrP = (unsigned short*)(ws + alloc((size_t)E * 12 * 2));
    unsigned*       degu   = (unsigned*)(ws + alloc((size_t)N * 4));
    unsigned*       curp   = (unsigned*)(ws + alloc((size_t)N * 4));
    unsigned*       offs   = (unsigned*)(ws + alloc((size_t)N * 4));
    unsigned*       bsum   = (unsigned*)(ws + alloc(64 * 4));
    unsigned short* W1T    = (unsigned short*)(ws + alloc(128 * K1 * 2));
    unsigned short* W2T    = (unsigned short*)(ws + alloc(64 * HID * 2));
    unsigned short* WST    = (unsigned short*)(ws + alloc(3 * 128 * 256 * 2));

    hipMemsetAsync(degu, 0, (size_t)N * sizeof(unsigned), stream);
    hist_kernel<<<(E + 255) / 256, 256, 0, stream>>>(dstp, degu, E);
    int NB = (N + 2047) / 2048;   // 49 for N=100000, fits the 64-lane bsum scan
    scan_partial<<<NB, 256, 0, stream>>>(degu, offs, bsum, N);
    scan_bsum<<<1, 64, 0, stream>>>(bsum, NB);
    scan_add<<<(N + 255) / 256, 256, 0, stream>>>(offs, bsum, curp, N);
    csr_fill<<<(E + 255) / 256, 256, 0, stream>>>(src, dstp, eattr, offs, curp,
                                                  csrS, csrD, csrE, eattrP, E);

    int prepTotal = 128 * K1 + 64 * HID + 3 * 128 * 256;
    prep_weights<<<(prepTotal + 255) / 256, 256, 0, stream>>>(W1, W2, sage_Wl, sage_Wr, W1T, W2T, WST);

    node_proj_kernel<<<(N * 64 + 255) / 256, 256, 0, stream>>>(x, node_W, node_b, hbf, N);

    int nblk = (N + 127) / 128;
    for (int l = 0; l < 2; l++) {
        agg_csr<<<(N + 15) / 16, 256, 0, stream>>>(hbf, csrS, offs, degu, meanbf, N);
        sage_mfma<<<nblk, 256, 0, stream>>>(
            hbf, meanbf, WST + (size_t)l * 128 * 256,
            sage_bl + (size_t)l * HID, ln_g + (size_t)l * HID, ln_b + (size_t)l * HID, N);
    }
    // final layer: fused SAGE + P/Q (P over hbf, Q over meanbf)
    agg_csr<<<(N + 15) / 16, 256, 0, stream>>>(hbf, csrS, offs, degu, meanbf, N);
    sage_pq_mfma<<<nblk, 256, 0, stream>>>(
        hbf, meanbf, WST + (size_t)2 * 128 * 256,
        sage_bl + (size_t)2 * HID, ln_g + (size_t)2 * HID, ln_b + (size_t)2 * HID, W1T, N);

    edge_mlp_mfma<<<(E + ET - 1) / ET, 256, 0, stream>>>(
        hbf, meanbf, csrS, csrD, csrE, eattrP, W1T, b1, W2T, b2, W3, b3, out, E);
}